// Round 18
// baseline (93.089 us; speedup 1.0000x reference)
//
#include <hip/hip_runtime.h>
#include <hip/hip_bf16.h>
#include <hip/hip_fp16.h>
#include <cmath>

#define NF 64
#define GRP 8
#define CG 8
#define KK 9
#define HH 128
#define WWID 128
#define BB 4
#define HWSZ (HH * WWID)
#define C_OM 216
#define OMS 292   // om LDS px-stride in halfs
#define DPS 74    // staged-row px-stride in halfs (37 dwords -> 2-way-max banks)

typedef __attribute__((ext_vector_type(8))) short bf16x8;
typedef __attribute__((ext_vector_type(8))) _Float16 f16x8;
typedef __attribute__((ext_vector_type(4))) float f32x4;

__device__ inline unsigned short f2bf(float f) {
    union { float f; unsigned u; } x; x.f = f;
    unsigned r = x.u + 0x7fff + ((x.u >> 16) & 1);   // RNE
    return (unsigned short)(r >> 16);
}

// ---------------------------------------------------------------------------
// PREP: blocks 0..1023 = NCHW fp32 (nbr++ref) -> NHWC bf16 [B][H][W][128]
//       + group-major FP16 gather buffer gm[B][G][H][W][8].  float4 loads.
//       blocks 1024+   = weight repacks (wf1 bf16, wf2 bf16, wdf fp16).
// ---------------------------------------------------------------------------
__global__ __launch_bounds__(256) void prep_kernel(
    const float* __restrict__ nbr, const float* __restrict__ ref,
    const float* __restrict__ w1, const float* __restrict__ wom,
    const float* __restrict__ wdcn,
    unsigned short* __restrict__ out, unsigned short* __restrict__ gm,
    unsigned short* __restrict__ wf1, unsigned short* __restrict__ wf2,
    unsigned short* __restrict__ wdf)
{
    __shared__ unsigned short lds[64 * 136];
    __shared__ __half lds_h[64 * 72];
    const int tid = threadIdx.x;

    if (blockIdx.x < 1024) {
        const int blk = blockIdx.x;
        const int b = blk >> 8, rem = blk & 255, y = rem >> 1, x0 = (rem & 1) * 64;
        const size_t rowoff = (size_t)y * WWID + x0;

#pragma unroll
        for (int it = 0; it < 8; ++it) {
            int idx = it * 256 + tid;          // 0..2047
            int c = idx >> 4, p4 = idx & 15;
            const float* src = (c < NF) ? (nbr + (size_t)(b * NF + c) * HWSZ)
                                        : (ref + (size_t)(b * NF + c - NF) * HWSZ);
            const float4 v = *(const float4*)(src + rowoff + p4 * 4);
            const float vv[4] = {v.x, v.y, v.z, v.w};
#pragma unroll
            for (int k = 0; k < 4; ++k) {
                const int p = p4 * 4 + k;
                lds[p * 136 + c] = f2bf(vv[k]);
                if (c < 64) lds_h[p * 72 + c] = __float2half(vv[k]);
            }
        }
        __syncthreads();
        const int p = tid >> 2, c0 = (tid & 3) * 32;
        unsigned short* dst = out + ((size_t)b * HWSZ + rowoff + p) * 128 + c0;
#pragma unroll
        for (int i = 0; i < 8; ++i)
            *(int2*)(dst + i * 4) = *(const int2*)&lds[p * 136 + c0 + i * 4];
        if (c0 < 64) {
#pragma unroll
            for (int gi = 0; gi < 4; ++gi) {
                const int g = (c0 >> 3) + gi;
                *(int4*)(gm + (((size_t)(b * 8 + g)) * HWSZ + rowoff + p) * 8) =
                    *(const int4*)&lds_h[p * 72 + g * 8];
            }
        }
        return;
    }

    int idx = (blockIdx.x - 1024) * 256 + tid;
    if (idx < 73728) {                 // conv1 A-frags [36][4][64][8] bf16
        int j = idx & 7, lane = (idx >> 3) & 63, t = idx >> 9;
        int mt = t % 4, kt = t / 4;
        int c0 = (kt / 9) * 32, tap = kt - (kt / 9) * 9;
        int cout = mt * 16 + (lane & 15);
        int cin = c0 + ((lane >> 4) * 8) + j;
        wf1[idx] = f2bf(w1[((size_t)cout * 128 + cin) * KK + tap]);
        return;
    }
    idx -= 73728;
    if (idx < 129024) {                // om A-frags [18][14][64][8] bf16
        int j = idx & 7, lane = (idx >> 3) & 63, t = idx >> 9;
        int mt = t % 14, kt = t / 14;
        int c0 = (kt / 9) * 32, tap = kt - (kt / 9) * 9;
        int cout = mt * 16 + (lane & 15);
        int cin = c0 + ((lane >> 4) * 8) + j;
        float v = (cout < C_OM) ? wom[((size_t)cout * 64 + cin) * KK + tap] : 0.f;
        wf2[idx] = f2bf(v);
        return;
    }
    idx -= 129024;
    if (idx < 36864) {                 // dcn A-frags [18][4][64][8] fp16
        int j = idx & 7, lane = (idx >> 3) & 63, t = idx >> 9;
        int mt = t & 3, s = t >> 2;
        int cout = mt * 16 + (lane & 15);
        int kglob = s * 32 + (lane >> 4) * 8 + j;
        int gk = kglob >> 3, c = kglob & 7;
        int g = gk / 9, kt = gk - g * 9;
        const __half hv = __float2half(wdcn[((size_t)cout * NF + g * 8 + c) * 9 + kt]);
        wdf[idx] = *(const unsigned short*)&hv;
    }
}

// ---------------------------------------------------------------------------
// conv1 (128ch -> 64ch, 3x3, lrelu), LDS row staging + A-frag double-buffer.
// XCD-contiguous swizzle + async pass-2 stage (R16). DPS=74 (R17).
// ---------------------------------------------------------------------------
__global__ __launch_bounds__(256) void conv1_kernel(
    const unsigned short* __restrict__ in,   // NHWC bf16 [B][H][W][128]
    const unsigned short* __restrict__ wf,   // A-frags [36][4][64][8]
    const float* __restrict__ bias,
    unsigned short* __restrict__ dst)        // NHWC bf16 [B][H][W][64]
{
    __shared__ unsigned short st[3 * 66 * DPS];   // 29,304 B

    const int tid = threadIdx.x;
    const int lane = tid & 63;
    const int wv = tid >> 6;
    const int raw = blockIdx.x;
    const int ng = (raw & 7) * 128 + (raw >> 3);  // XCD-contiguous (1024 % 8 == 0)
    const int b = ng >> 8, rem = ng & 255;
    const int y = rem >> 1, x0 = (rem & 1) * 64;
    const int ln = lane & 15, kb = lane >> 4;

    f32x4 acc[4];
#pragma unroll
    for (int nt = 0; nt < 4; ++nt) acc[nt] = f32x4{0.f, 0.f, 0.f, 0.f};

    const unsigned short* inb = in + (size_t)b * HWSZ * 128;

    // ---- pass-1 staging (ch 0..63) direct global->LDS ----
    for (int i = tid; i < 3 * 66 * 8; i += 256) {
        const int j = i & 7, t = i >> 3;
        const int px = t % 66, r = t / 66;
        const int yy = y + r - 1, xx = x0 + px - 1;
        int4 v = {0, 0, 0, 0};
        if ((unsigned)yy < (unsigned)HH && (unsigned)xx < (unsigned)WWID)
            v = *(const int4*)(inb + ((size_t)yy * WWID + xx) * 128 + j * 8);
        *(int4*)&st[(r * 66 + px) * DPS + j * 8] = v;
    }
    __syncthreads();

    // ---- T14: issue pass-2 (ch 64..127) global loads into registers ----
    int4 rg[7];
#pragma unroll
    for (int k = 0; k < 7; ++k) {
        const int i = tid + k * 256;
        int4 v = {0, 0, 0, 0};
        if (i < 3 * 66 * 8) {
            const int j = i & 7, t = i >> 3;
            const int px = t % 66, r = t / 66;
            const int yy = y + r - 1, xx = x0 + px - 1;
            if ((unsigned)yy < (unsigned)HH && (unsigned)xx < (unsigned)WWID)
                v = *(const int4*)(inb + ((size_t)yy * WWID + xx) * 128 + 64 + j * 8);
        }
        rg[k] = v;
    }

    auto compute = [&](int base_kt) {
        bf16x8 afA, afB;
        afA = *(const bf16x8*)(wf + (((size_t)base_kt * 4 + wv) * 64 + lane) * 8);
#pragma unroll
        for (int step = 0; step < 18; ++step) {
            const int cc = (step / 9) * 32;
            const int tap = step % 9;
            const int ky = tap / 3, kx = tap % 3;

            if (step < 17) {
                const int kt1 = base_kt + step + 1;
                bf16x8* alt = (step & 1) ? &afA : &afB;
                *alt = *(const bf16x8*)(wf + (((size_t)kt1 * 4 + wv) * 64 + lane) * 8);
            }

            bf16x8 bfrag[4];
#pragma unroll
            for (int nt = 0; nt < 4; ++nt) {
                const int px = nt * 16 + ln + kx;
                bfrag[nt] = *(const bf16x8*)&st[(ky * 66 + px) * DPS + cc + kb * 8];
            }

            const bf16x8 cur = (step & 1) ? afB : afA;
#pragma unroll
            for (int nt = 0; nt < 4; ++nt)
                acc[nt] = __builtin_amdgcn_mfma_f32_16x16x32_bf16(
                    cur, bfrag[nt], acc[nt], 0, 0, 0);
        }
    };

    compute(0);            // ch 0..63  (kt 0..17); pass-2 loads in flight
    __syncthreads();

    // ---- T14: dump pass-2 registers to LDS ----
#pragma unroll
    for (int k = 0; k < 7; ++k) {
        const int i = tid + k * 256;
        if (i < 3 * 66 * 8) {
            const int j = i & 7, t = i >> 3;
            const int px = t % 66, r = t / 66;
            *(int4*)&st[(r * 66 + px) * DPS + j * 8] = rg[k];
        }
    }
    __syncthreads();

    compute(18);           // ch 64..127 (kt 18..35)

    const int cout = wv * 16 + kb * 4;
    const float b0 = bias[cout], b1 = bias[cout + 1];
    const float b2 = bias[cout + 2], b3 = bias[cout + 3];
#pragma unroll
    for (int nt = 0; nt < 4; ++nt) {
        const int px = x0 + nt * 16 + ln;
        const size_t pix = (size_t)b * HWSZ + (size_t)y * WWID + px;
        f32x4 v = acc[nt];
        v[0] += b0; v[1] += b1; v[2] += b2; v[3] += b3;
#pragma unroll
        for (int r = 0; r < 4; ++r) v[r] = (v[r] >= 0.f) ? v[r] : 0.1f * v[r];
        int2 pk;
        pk.x = (int)f2bf(v[0]) | ((int)f2bf(v[1]) << 16);
        pk.y = (int)f2bf(v[2]) | ((int)f2bf(v[3]) << 16);
        *(int2*)(dst + pix * 64 + cout) = pk;
    }
}

// ---------------------------------------------------------------------------
// FUSED conv_om + DCN. Block = 512 thr / 8 waves / 128 px (full row),
// grid 512 (2 blocks/CU, 16 waves/CU). R12 structure; DPS=74 (R17).
// ---------------------------------------------------------------------------
__global__ __launch_bounds__(512, 4) void dcn_fused_kernel(
    const unsigned short* __restrict__ off_f,   // NHWC bf16 [B][H][W][64]
    const unsigned short* __restrict__ gm,      // gmajor FP16 [B][G][H][W][8]
    const unsigned short* __restrict__ wf2,     // om A-frags bf16 (MT=14)
    const float* __restrict__ bom,
    const unsigned short* __restrict__ wdf,     // dcn A-frags FP16
    const float* __restrict__ bdcn,
    float* __restrict__ out)
{
    __shared__ unsigned short smem[128 * OMS];  // 74,752 B (stage/om union)

    const int raw = blockIdx.x;                 // 0..511
    const int bid = (raw & 7) * 64 + (raw >> 3);    // XCD-contiguous
    const int b = bid >> 7;
    const int y = bid & 127;

    const int tid = threadIdx.x;
    const int lane = tid & 63;
    const int wv = tid >> 6;                    // 0..7
    const int ln = lane & 15, kb = lane >> 4;

    // ---------------- Stage off_f rows (3 x 130 x 64ch) into LDS ----------
    for (int i = tid; i < 3 * 130 * 8; i += 512) {
        const int j = i & 7, t = i >> 3;
        const int px = t % 130, r = t / 130;
        const int yy = y + r - 1, xx = px - 1;
        int4 v = {0, 0, 0, 0};
        if ((unsigned)yy < (unsigned)HH && (unsigned)xx < (unsigned)WWID)
            v = *(const int4*)(off_f + ((size_t)b * HWSZ + yy * WWID + xx) * 64 + j * 8);
        *(int4*)&smem[(r * 130 + px) * DPS + j * 8] = v;
    }
    __syncthreads();

    // ---------------- Phase 1: om GEMM (M=224 pad, N=128, K=576) ----------
    // Wave wv owns M-tiles {wv, wv+8} (wv>=6: one tile). A double-buffered.
    f32x4 acc1[2][8];
#pragma unroll
    for (int i = 0; i < 2; ++i)
#pragma unroll
        for (int j = 0; j < 8; ++j) acc1[i][j] = f32x4{0.f, 0.f, 0.f, 0.f};

    {
        bf16x8 afA[2], afB[2];
#pragma unroll
        for (int i = 0; i < 2; ++i) {
            const int mt = wv + 8 * i;
            afA[i] = (mt < 14)
                ? ((const bf16x8*)wf2)[(size_t)mt * 64 + lane]
                : bf16x8{};
        }

#pragma unroll
        for (int step = 0; step < 18; ++step) {
            const int cc = (step / 9) * 32;
            const int tap = step % 9;
            const int ky = tap / 3, kx = tap % 3;

            if (step < 17) {
                const int kt1 = step + 1;
                bf16x8* alt = (step & 1) ? afA : afB;
#pragma unroll
                for (int i = 0; i < 2; ++i) {
                    const int mt = wv + 8 * i;
                    alt[i] = (mt < 14)
                        ? ((const bf16x8*)wf2)[(size_t)kt1 * 14 * 64 + (size_t)mt * 64 + lane]
                        : bf16x8{};
                }
            }

            bf16x8 bfrag[8];
#pragma unroll
            for (int nt = 0; nt < 8; ++nt) {
                const int px = nt * 16 + ln + kx;
                bfrag[nt] = *(const bf16x8*)&smem[(ky * 130 + px) * DPS + cc + kb * 8];
            }

            const bf16x8* cur = (step & 1) ? afB : afA;
#pragma unroll
            for (int i = 0; i < 2; ++i) {
                const int mt = wv + 8 * i;
                if (mt < 14) {
#pragma unroll
                    for (int nt = 0; nt < 8; ++nt)
                        acc1[i][nt] = __builtin_amdgcn_mfma_f32_16x16x32_bf16(
                            cur[i], bfrag[nt], acc1[i][nt], 0, 0, 0);
                }
            }
        }
    }
    __syncthreads();    // all stage reads done; smem may be overwritten

    // ------- om epilogue -> LDS fp16 quads, sigmoid fused on field 2 -------
    __half* smh = (__half*)smem;
#pragma unroll
    for (int i = 0; i < 2; ++i) {
        const int mt = wv + 8 * i;
        if (mt >= 14) continue;
        const int cb = mt * 16 + kb * 4;
#pragma unroll
        for (int nt = 0; nt < 8; ++nt) {
            const int px = nt * 16 + ln;
#pragma unroll
            for (int r = 0; r < 4; ++r) {
                const int c = cb + r;
                if (c < C_OM) {
                    const int field = (c >= 144) ? 2 : ((c >= 72) ? 1 : 0);
                    const int gk = c - field * 72;
                    float v = acc1[i][nt][r] + bom[c];
                    if (field == 2) v = 1.f / (1.f + __expf(-v));
                    smh[px * OMS + gk * 4 + field] = __float2half(v);
                }
            }
        }
    }
    __syncthreads();

    // ---------------- Phase 2: sampling + einsum (full K per wave) ---------
    const int pxl = wv * 16 + ln;      // 0..127
    const int x = pxl;

    f32x4 acc[4];
#pragma unroll
    for (int mt = 0; mt < 4; ++mt) acc[mt] = f32x4{0.f, 0.f, 0.f, 0.f};

    const unsigned short* gmb = gm + (size_t)b * 8 * HWSZ * 8;

#pragma unroll
    for (int ch = 0; ch < 3; ++ch) {
        short4 q[6];
#pragma unroll
        for (int i = 0; i < 6; ++i) {
            const int gk = (ch * 6 + i) * 4 + kb;
            q[i] = *(const short4*)&smh[pxl * OMS + gk * 4];
        }

#pragma unroll
        for (int i = 0; i < 6; ++i) {
            const int s = ch * 6 + i;
            const int gk = s * 4 + kb;
            const int g = gk / 9;
            const int kt = gk - g * 9;

            const float oy = __half2float(((const __half*)&q[i])[0]);
            const float ox = __half2float(((const __half*)&q[i])[1]);
            const float mv = __half2float(((const __half*)&q[i])[2]);  // sigmoided

            const float pyf = (float)(y + kt / 3 - 1) + oy;
            const float pxf = (float)(x + kt % 3 - 1) + ox;
            const float fy = floorf(pyf), fx = floorf(pxf);
            const float wy = pyf - fy, wx = pxf - fx;
            const int iy = (int)fy, ix = (int)fx;

            float w00 = (1.f - wy) * (1.f - wx);
            float w01 = (1.f - wy) * wx;
            float w10 = wy * (1.f - wx);
            float w11 = wy * wx;

            const bool vy0 = (iy >= 0) && (iy < HH);
            const bool vy1 = (iy + 1 >= 0) && (iy + 1 < HH);
            const bool vx0 = (ix >= 0) && (ix < WWID);
            const bool vx1 = (ix + 1 >= 0) && (ix + 1 < WWID);
            w00 *= (vy0 && vx0) ? mv : 0.f;
            w01 *= (vy0 && vx1) ? mv : 0.f;
            w10 *= (vy1 && vx0) ? mv : 0.f;
            w11 *= (vy1 && vx1) ? mv : 0.f;

            const int y0c = min(max(iy, 0), HH - 1);
            const int y1c = min(max(iy + 1, 0), HH - 1);
            const int x0c = min(max(ix, 0), WWID - 1);
            const int x1c = min(max(ix + 1, 0), WWID - 1);
            const int sel = x1c - x0c;

            const float wl0 = w00 + (sel ? 0.f : w01);
            const float wh0 = sel ? w01 : 0.f;
            const float wl1 = w10 + (sel ? 0.f : w11);
            const float wh1 = sel ? w11 : 0.f;

            const unsigned short* pgm = gmb + (size_t)g * HWSZ * 8;
            const size_t rec0 = (size_t)(y0c * WWID + x0c) * 8;
            const size_t rec1 = (size_t)(y1c * WWID + x0c) * 8;
            int4 L0 = *(const int4*)(pgm + rec0);
            int4 H0 = *(const int4*)(pgm + rec0 + 8);
            int4 L1 = *(const int4*)(pgm + rec1);
            int4 H1 = *(const int4*)(pgm + rec1 + 8);

            const __half2 wl0h = __float2half2_rn(wl0);
            const __half2 wh0h = __float2half2_rn(wh0);
            const __half2 wl1h = __float2half2_rn(wl1);
            const __half2 wh1h = __float2half2_rn(wh1);
            const __half2* l0 = (const __half2*)&L0;
            const __half2* h0 = (const __half2*)&H0;
            const __half2* l1 = (const __half2*)&L1;
            const __half2* h1 = (const __half2*)&H1;
            __half2 bp0 = __hfma2(l0[0], wl0h, __hfma2(h0[0], wh0h,
                          __hfma2(l1[0], wl1h, __hmul2(h1[0], wh1h))));
            __half2 bp1 = __hfma2(l0[1], wl0h, __hfma2(h0[1], wh0h,
                          __hfma2(l1[1], wl1h, __hmul2(h1[1], wh1h))));
            __half2 bp2 = __hfma2(l0[2], wl0h, __hfma2(h0[2], wh0h,
                          __hfma2(l1[2], wl1h, __hmul2(h1[2], wh1h))));
            __half2 bp3 = __hfma2(l0[3], wl0h, __hfma2(h0[3], wh0h,
                          __hfma2(l1[3], wl1h, __hmul2(h1[3], wh1h))));
            __half2 bpv[4] = {bp0, bp1, bp2, bp3};
            const f16x8 bfrag = *(const f16x8*)bpv;

            const f16x8* af = (const f16x8*)wdf + ((size_t)s * 4) * 64 + lane;
#pragma unroll
            for (int mt = 0; mt < 4; ++mt)
                acc[mt] = __builtin_amdgcn_mfma_f32_16x16x32_f16(
                    af[(size_t)mt * 64], bfrag, acc[mt], 0, 0, 0);
        }
    }

    // ---------------- Epilogue: direct store -------------------------------
#pragma unroll
    for (int mt = 0; mt < 4; ++mt) {
#pragma unroll
        for (int r = 0; r < 4; ++r) {
            const int cout = mt * 16 + kb * 4 + r;
            float v = acc[mt][r] + bdcn[cout];
            v = (v >= 0.f) ? v : 0.1f * v;
            out[((size_t)(b * NF + cout)) * HWSZ + (size_t)y * WWID + x] = v;
        }
    }
}

// ---------------------------------------------------------------------------
extern "C" void kernel_launch(void* const* d_in, const int* in_sizes, int n_in,
                              void* d_out, int out_size, void* d_ws, size_t ws_size,
                              hipStream_t stream)
{
    const float* nbr  = (const float*)d_in[0];
    const float* ref  = (const float*)d_in[1];
    const float* w1   = (const float*)d_in[2];
    const float* b1   = (const float*)d_in[3];
    const float* wom  = (const float*)d_in[4];
    const float* bom  = (const float*)d_in[5];
    const float* wdcn = (const float*)d_in[6];
    const float* bdcn = (const float*)d_in[7];
    float* out = (float*)d_out;

    const size_t NH_B  = (size_t)BB * HWSZ * 128 * 2;     // 16,777,216
    const size_t OFF_B = (size_t)BB * HWSZ * 64 * 2;      //  8,388,608
    const size_t GM_B  = (size_t)BB * HWSZ * 64 * 2 + 64; // + overread pad
    const size_t WF1_B = 36 * 4 * 512 * 2;                //    147,456
    const size_t WF2_B = 18 * 14 * 512 * 2;               //    258,048

    char* ws = (char*)d_ws;
    unsigned short* nhwcin = (unsigned short*)ws;
    unsigned short* off_f  = (unsigned short*)(ws + NH_B);
    unsigned short* gm     = (unsigned short*)(ws + NH_B + OFF_B);
    unsigned short* wf1    = (unsigned short*)(ws + NH_B + OFF_B + GM_B);
    unsigned short* wf2    = wf1 + WF1_B / 2;
    unsigned short* wdf    = wf2 + WF2_B / 2;

    // 1) prep: transpose (NHWC128 bf16 + fp16 gm) and all weight repacks
    prep_kernel<<<1024 + 936, 256, 0, stream>>>(
        nbr, ref, w1, wom, wdcn, nhwcin, gm, wf1, wf2, wdf);

    // 2) conv1: staged-LDS implicit GEMM, XCD swizzle + async pass-2 stage
    conv1_kernel<<<1024, 256, 0, stream>>>(nhwcin, wf1, b1, off_f);

    // 3) fused conv_om + deformable conv (128-px blocks, 8 waves)
    dcn_fused_kernel<<<512, 512, 0, stream>>>(
        off_f, gm, wf2, bom, wdf, bdcn, out);
}

// Round 19
// 86.958 us; speedup vs baseline: 1.0705x; 1.0705x over previous
//
#include <hip/hip_runtime.h>
#include <hip/hip_bf16.h>
#include <hip/hip_fp16.h>
#include <cmath>

#define NF 64
#define GRP 8
#define CG 8
#define KK 9
#define HH 128
#define WWID 128
#define BB 4
#define HWSZ (HH * WWID)
#define C_OM 216
#define OMS 292   // om LDS px-stride in halfs
#define DPS 72    // staged-row px-stride in halfs (64ch + 8 pad; empirically best)

typedef __attribute__((ext_vector_type(8))) short bf16x8;
typedef __attribute__((ext_vector_type(8))) _Float16 f16x8;
typedef __attribute__((ext_vector_type(4))) float f32x4;

__device__ inline unsigned short f2bf(float f) {
    union { float f; unsigned u; } x; x.f = f;
    unsigned r = x.u + 0x7fff + ((x.u >> 16) & 1);   // RNE
    return (unsigned short)(r >> 16);
}

// ---------------------------------------------------------------------------
// PREP: blocks 0..1023 = NCHW fp32 (nbr++ref) -> NHWC bf16 [B][H][W][128]
//       + group-major FP16 gather buffer gm[B][G][H][W][8].  float4 loads.
//       blocks 1024+   = weight repacks (wf1 bf16, wf2 bf16, wdf fp16).
// ---------------------------------------------------------------------------
__global__ __launch_bounds__(256) void prep_kernel(
    const float* __restrict__ nbr, const float* __restrict__ ref,
    const float* __restrict__ w1, const float* __restrict__ wom,
    const float* __restrict__ wdcn,
    unsigned short* __restrict__ out, unsigned short* __restrict__ gm,
    unsigned short* __restrict__ wf1, unsigned short* __restrict__ wf2,
    unsigned short* __restrict__ wdf)
{
    __shared__ unsigned short lds[64 * 136];
    __shared__ __half lds_h[64 * 72];
    const int tid = threadIdx.x;

    if (blockIdx.x < 1024) {
        const int blk = blockIdx.x;
        const int b = blk >> 8, rem = blk & 255, y = rem >> 1, x0 = (rem & 1) * 64;
        const size_t rowoff = (size_t)y * WWID + x0;

#pragma unroll
        for (int it = 0; it < 8; ++it) {
            int idx = it * 256 + tid;          // 0..2047
            int c = idx >> 4, p4 = idx & 15;
            const float* src = (c < NF) ? (nbr + (size_t)(b * NF + c) * HWSZ)
                                        : (ref + (size_t)(b * NF + c - NF) * HWSZ);
            const float4 v = *(const float4*)(src + rowoff + p4 * 4);
            const float vv[4] = {v.x, v.y, v.z, v.w};
#pragma unroll
            for (int k = 0; k < 4; ++k) {
                const int p = p4 * 4 + k;
                lds[p * 136 + c] = f2bf(vv[k]);
                if (c < 64) lds_h[p * 72 + c] = __float2half(vv[k]);
            }
        }
        __syncthreads();
        const int p = tid >> 2, c0 = (tid & 3) * 32;
        unsigned short* dst = out + ((size_t)b * HWSZ + rowoff + p) * 128 + c0;
#pragma unroll
        for (int i = 0; i < 8; ++i)
            *(int2*)(dst + i * 4) = *(const int2*)&lds[p * 136 + c0 + i * 4];
        if (c0 < 64) {
#pragma unroll
            for (int gi = 0; gi < 4; ++gi) {
                const int g = (c0 >> 3) + gi;
                *(int4*)(gm + (((size_t)(b * 8 + g)) * HWSZ + rowoff + p) * 8) =
                    *(const int4*)&lds_h[p * 72 + g * 8];
            }
        }
        return;
    }

    int idx = (blockIdx.x - 1024) * 256 + tid;
    if (idx < 73728) {                 // conv1 A-frags [36][4][64][8] bf16
        int j = idx & 7, lane = (idx >> 3) & 63, t = idx >> 9;
        int mt = t % 4, kt = t / 4;
        int c0 = (kt / 9) * 32, tap = kt - (kt / 9) * 9;
        int cout = mt * 16 + (lane & 15);
        int cin = c0 + ((lane >> 4) * 8) + j;
        wf1[idx] = f2bf(w1[((size_t)cout * 128 + cin) * KK + tap]);
        return;
    }
    idx -= 73728;
    if (idx < 129024) {                // om A-frags [18][14][64][8] bf16
        int j = idx & 7, lane = (idx >> 3) & 63, t = idx >> 9;
        int mt = t % 14, kt = t / 14;
        int c0 = (kt / 9) * 32, tap = kt - (kt / 9) * 9;
        int cout = mt * 16 + (lane & 15);
        int cin = c0 + ((lane >> 4) * 8) + j;
        float v = (cout < C_OM) ? wom[((size_t)cout * 64 + cin) * KK + tap] : 0.f;
        wf2[idx] = f2bf(v);
        return;
    }
    idx -= 129024;
    if (idx < 36864) {                 // dcn A-frags [18][4][64][8] fp16
        int j = idx & 7, lane = (idx >> 3) & 63, t = idx >> 9;
        int mt = t & 3, s = t >> 2;
        int cout = mt * 16 + (lane & 15);
        int kglob = s * 32 + (lane >> 4) * 8 + j;
        int gk = kglob >> 3, c = kglob & 7;
        int g = gk / 9, kt = gk - g * 9;
        const __half hv = __float2half(wdcn[((size_t)cout * NF + g * 8 + c) * 9 + kt]);
        wdf[idx] = *(const unsigned short*)&hv;
    }
}

// ---------------------------------------------------------------------------
// conv1 (128ch -> 64ch, 3x3, lrelu), LDS row staging + A-frag double-buffer.
// XCD-contiguous block swizzle + async pass-2 stage (T14).
// ---------------------------------------------------------------------------
__global__ __launch_bounds__(256) void conv1_kernel(
    const unsigned short* __restrict__ in,   // NHWC bf16 [B][H][W][128]
    const unsigned short* __restrict__ wf,   // A-frags [36][4][64][8]
    const float* __restrict__ bias,
    unsigned short* __restrict__ dst)        // NHWC bf16 [B][H][W][64]
{
    __shared__ unsigned short st[3 * 66 * DPS];   // 28,512 B

    const int tid = threadIdx.x;
    const int lane = tid & 63;
    const int wv = tid >> 6;
    const int raw = blockIdx.x;
    const int ng = (raw & 7) * 128 + (raw >> 3);  // XCD-contiguous (1024 % 8 == 0)
    const int b = ng >> 8, rem = ng & 255;
    const int y = rem >> 1, x0 = (rem & 1) * 64;
    const int ln = lane & 15, kb = lane >> 4;

    f32x4 acc[4];
#pragma unroll
    for (int nt = 0; nt < 4; ++nt) acc[nt] = f32x4{0.f, 0.f, 0.f, 0.f};

    const unsigned short* inb = in + (size_t)b * HWSZ * 128;

    // ---- pass-1 staging (ch 0..63) direct global->LDS ----
    for (int i = tid; i < 3 * 66 * 8; i += 256) {
        const int j = i & 7, t = i >> 3;
        const int px = t % 66, r = t / 66;
        const int yy = y + r - 1, xx = x0 + px - 1;
        int4 v = {0, 0, 0, 0};
        if ((unsigned)yy < (unsigned)HH && (unsigned)xx < (unsigned)WWID)
            v = *(const int4*)(inb + ((size_t)yy * WWID + xx) * 128 + j * 8);
        *(int4*)&st[(r * 66 + px) * DPS + j * 8] = v;
    }
    __syncthreads();

    // ---- T14: issue pass-2 (ch 64..127) global loads into registers ----
    int4 rg[7];
#pragma unroll
    for (int k = 0; k < 7; ++k) {
        const int i = tid + k * 256;
        int4 v = {0, 0, 0, 0};
        if (i < 3 * 66 * 8) {
            const int j = i & 7, t = i >> 3;
            const int px = t % 66, r = t / 66;
            const int yy = y + r - 1, xx = x0 + px - 1;
            if ((unsigned)yy < (unsigned)HH && (unsigned)xx < (unsigned)WWID)
                v = *(const int4*)(inb + ((size_t)yy * WWID + xx) * 128 + 64 + j * 8);
        }
        rg[k] = v;
    }

    auto compute = [&](int base_kt) {
        bf16x8 afA, afB;
        afA = *(const bf16x8*)(wf + (((size_t)base_kt * 4 + wv) * 64 + lane) * 8);
#pragma unroll
        for (int step = 0; step < 18; ++step) {
            const int cc = (step / 9) * 32;
            const int tap = step % 9;
            const int ky = tap / 3, kx = tap % 3;

            if (step < 17) {
                const int kt1 = base_kt + step + 1;
                bf16x8* alt = (step & 1) ? &afA : &afB;
                *alt = *(const bf16x8*)(wf + (((size_t)kt1 * 4 + wv) * 64 + lane) * 8);
            }

            bf16x8 bfrag[4];
#pragma unroll
            for (int nt = 0; nt < 4; ++nt) {
                const int px = nt * 16 + ln + kx;
                bfrag[nt] = *(const bf16x8*)&st[(ky * 66 + px) * DPS + cc + kb * 8];
            }

            const bf16x8 cur = (step & 1) ? afB : afA;
#pragma unroll
            for (int nt = 0; nt < 4; ++nt)
                acc[nt] = __builtin_amdgcn_mfma_f32_16x16x32_bf16(
                    cur, bfrag[nt], acc[nt], 0, 0, 0);
        }
    };

    compute(0);            // ch 0..63  (kt 0..17); pass-2 loads in flight
    __syncthreads();

    // ---- T14: dump pass-2 registers to LDS ----
#pragma unroll
    for (int k = 0; k < 7; ++k) {
        const int i = tid + k * 256;
        if (i < 3 * 66 * 8) {
            const int j = i & 7, t = i >> 3;
            const int px = t % 66, r = t / 66;
            *(int4*)&st[(r * 66 + px) * DPS + j * 8] = rg[k];
        }
    }
    __syncthreads();

    compute(18);           // ch 64..127 (kt 18..35)

    const int cout = wv * 16 + kb * 4;
    const float b0 = bias[cout], b1 = bias[cout + 1];
    const float b2 = bias[cout + 2], b3 = bias[cout + 3];
#pragma unroll
    for (int nt = 0; nt < 4; ++nt) {
        const int px = x0 + nt * 16 + ln;
        const size_t pix = (size_t)b * HWSZ + (size_t)y * WWID + px;
        f32x4 v = acc[nt];
        v[0] += b0; v[1] += b1; v[2] += b2; v[3] += b3;
#pragma unroll
        for (int r = 0; r < 4; ++r) v[r] = (v[r] >= 0.f) ? v[r] : 0.1f * v[r];
        int2 pk;
        pk.x = (int)f2bf(v[0]) | ((int)f2bf(v[1]) << 16);
        pk.y = (int)f2bf(v[2]) | ((int)f2bf(v[3]) << 16);
        *(int2*)(dst + pix * 64 + cout) = pk;
    }
}

// ---------------------------------------------------------------------------
// FUSED conv_om + DCN. Block = 512 thr / 8 waves / 128 px (full row),
// grid 512 (2 blocks/CU, 16 waves/CU). Best-measured configuration:
// A-frag double-buffer, sigmoid fused in epilogue, 3 barriers total.
// ---------------------------------------------------------------------------
__global__ __launch_bounds__(512, 4) void dcn_fused_kernel(
    const unsigned short* __restrict__ off_f,   // NHWC bf16 [B][H][W][64]
    const unsigned short* __restrict__ gm,      // gmajor FP16 [B][G][H][W][8]
    const unsigned short* __restrict__ wf2,     // om A-frags bf16 (MT=14)
    const float* __restrict__ bom,
    const unsigned short* __restrict__ wdf,     // dcn A-frags FP16
    const float* __restrict__ bdcn,
    float* __restrict__ out)
{
    __shared__ unsigned short smem[128 * OMS];  // 74,752 B (stage/om union)

    const int raw = blockIdx.x;                 // 0..511
    const int bid = (raw & 7) * 64 + (raw >> 3);    // XCD-contiguous
    const int b = bid >> 7;
    const int y = bid & 127;

    const int tid = threadIdx.x;
    const int lane = tid & 63;
    const int wv = tid >> 6;                    // 0..7
    const int ln = lane & 15, kb = lane >> 4;

    // ---------------- Stage off_f rows (3 x 130 x 64ch) into LDS ----------
    for (int i = tid; i < 3 * 130 * 8; i += 512) {
        const int j = i & 7, t = i >> 3;
        const int px = t % 130, r = t / 130;
        const int yy = y + r - 1, xx = px - 1;
        int4 v = {0, 0, 0, 0};
        if ((unsigned)yy < (unsigned)HH && (unsigned)xx < (unsigned)WWID)
            v = *(const int4*)(off_f + ((size_t)b * HWSZ + yy * WWID + xx) * 64 + j * 8);
        *(int4*)&smem[(r * 130 + px) * DPS + j * 8] = v;
    }
    __syncthreads();

    // ---------------- Phase 1: om GEMM (M=224 pad, N=128, K=576) ----------
    // Wave wv owns M-tiles {wv, wv+8} (wv>=6: one tile). A double-buffered.
    f32x4 acc1[2][8];
#pragma unroll
    for (int i = 0; i < 2; ++i)
#pragma unroll
        for (int j = 0; j < 8; ++j) acc1[i][j] = f32x4{0.f, 0.f, 0.f, 0.f};

    {
        bf16x8 afA[2], afB[2];
#pragma unroll
        for (int i = 0; i < 2; ++i) {
            const int mt = wv + 8 * i;
            afA[i] = (mt < 14)
                ? ((const bf16x8*)wf2)[(size_t)mt * 64 + lane]
                : bf16x8{};
        }

#pragma unroll
        for (int step = 0; step < 18; ++step) {
            const int cc = (step / 9) * 32;
            const int tap = step % 9;
            const int ky = tap / 3, kx = tap % 3;

            if (step < 17) {
                const int kt1 = step + 1;
                bf16x8* alt = (step & 1) ? afA : afB;
#pragma unroll
                for (int i = 0; i < 2; ++i) {
                    const int mt = wv + 8 * i;
                    alt[i] = (mt < 14)
                        ? ((const bf16x8*)wf2)[(size_t)kt1 * 14 * 64 + (size_t)mt * 64 + lane]
                        : bf16x8{};
                }
            }

            bf16x8 bfrag[8];
#pragma unroll
            for (int nt = 0; nt < 8; ++nt) {
                const int px = nt * 16 + ln + kx;
                bfrag[nt] = *(const bf16x8*)&smem[(ky * 130 + px) * DPS + cc + kb * 8];
            }

            const bf16x8* cur = (step & 1) ? afB : afA;
#pragma unroll
            for (int i = 0; i < 2; ++i) {
                const int mt = wv + 8 * i;
                if (mt < 14) {
#pragma unroll
                    for (int nt = 0; nt < 8; ++nt)
                        acc1[i][nt] = __builtin_amdgcn_mfma_f32_16x16x32_bf16(
                            cur[i], bfrag[nt], acc1[i][nt], 0, 0, 0);
                }
            }
        }
    }
    __syncthreads();    // all stage reads done; smem may be overwritten

    // ------- om epilogue -> LDS fp16 quads, sigmoid fused on field 2 -------
    __half* smh = (__half*)smem;
#pragma unroll
    for (int i = 0; i < 2; ++i) {
        const int mt = wv + 8 * i;
        if (mt >= 14) continue;
        const int cb = mt * 16 + kb * 4;
#pragma unroll
        for (int nt = 0; nt < 8; ++nt) {
            const int px = nt * 16 + ln;
#pragma unroll
            for (int r = 0; r < 4; ++r) {
                const int c = cb + r;
                if (c < C_OM) {
                    const int field = (c >= 144) ? 2 : ((c >= 72) ? 1 : 0);
                    const int gk = c - field * 72;
                    float v = acc1[i][nt][r] + bom[c];
                    if (field == 2) v = 1.f / (1.f + __expf(-v));
                    smh[px * OMS + gk * 4 + field] = __float2half(v);
                }
            }
        }
    }
    __syncthreads();

    // ---------------- Phase 2: sampling + einsum (full K per wave) ---------
    const int pxl = wv * 16 + ln;      // 0..127
    const int x = pxl;

    f32x4 acc[4];
#pragma unroll
    for (int mt = 0; mt < 4; ++mt) acc[mt] = f32x4{0.f, 0.f, 0.f, 0.f};

    const unsigned short* gmb = gm + (size_t)b * 8 * HWSZ * 8;

#pragma unroll
    for (int ch = 0; ch < 3; ++ch) {
        short4 q[6];
#pragma unroll
        for (int i = 0; i < 6; ++i) {
            const int gk = (ch * 6 + i) * 4 + kb;
            q[i] = *(const short4*)&smh[pxl * OMS + gk * 4];
        }

#pragma unroll
        for (int i = 0; i < 6; ++i) {
            const int s = ch * 6 + i;
            const int gk = s * 4 + kb;
            const int g = gk / 9;
            const int kt = gk - g * 9;

            const float oy = __half2float(((const __half*)&q[i])[0]);
            const float ox = __half2float(((const __half*)&q[i])[1]);
            const float mv = __half2float(((const __half*)&q[i])[2]);  // sigmoided

            const float pyf = (float)(y + kt / 3 - 1) + oy;
            const float pxf = (float)(x + kt % 3 - 1) + ox;
            const float fy = floorf(pyf), fx = floorf(pxf);
            const float wy = pyf - fy, wx = pxf - fx;
            const int iy = (int)fy, ix = (int)fx;

            float w00 = (1.f - wy) * (1.f - wx);
            float w01 = (1.f - wy) * wx;
            float w10 = wy * (1.f - wx);
            float w11 = wy * wx;

            const bool vy0 = (iy >= 0) && (iy < HH);
            const bool vy1 = (iy + 1 >= 0) && (iy + 1 < HH);
            const bool vx0 = (ix >= 0) && (ix < WWID);
            const bool vx1 = (ix + 1 >= 0) && (ix + 1 < WWID);
            w00 *= (vy0 && vx0) ? mv : 0.f;
            w01 *= (vy0 && vx1) ? mv : 0.f;
            w10 *= (vy1 && vx0) ? mv : 0.f;
            w11 *= (vy1 && vx1) ? mv : 0.f;

            const int y0c = min(max(iy, 0), HH - 1);
            const int y1c = min(max(iy + 1, 0), HH - 1);
            const int x0c = min(max(ix, 0), WWID - 1);
            const int x1c = min(max(ix + 1, 0), WWID - 1);
            const int sel = x1c - x0c;

            const float wl0 = w00 + (sel ? 0.f : w01);
            const float wh0 = sel ? w01 : 0.f;
            const float wl1 = w10 + (sel ? 0.f : w11);
            const float wh1 = sel ? w11 : 0.f;

            const unsigned short* pgm = gmb + (size_t)g * HWSZ * 8;
            const size_t rec0 = (size_t)(y0c * WWID + x0c) * 8;
            const size_t rec1 = (size_t)(y1c * WWID + x0c) * 8;
            int4 L0 = *(const int4*)(pgm + rec0);
            int4 H0 = *(const int4*)(pgm + rec0 + 8);
            int4 L1 = *(const int4*)(pgm + rec1);
            int4 H1 = *(const int4*)(pgm + rec1 + 8);

            const __half2 wl0h = __float2half2_rn(wl0);
            const __half2 wh0h = __float2half2_rn(wh0);
            const __half2 wl1h = __float2half2_rn(wl1);
            const __half2 wh1h = __float2half2_rn(wh1);
            const __half2* l0 = (const __half2*)&L0;
            const __half2* h0 = (const __half2*)&H0;
            const __half2* l1 = (const __half2*)&L1;
            const __half2* h1 = (const __half2*)&H1;
            __half2 bp0 = __hfma2(l0[0], wl0h, __hfma2(h0[0], wh0h,
                          __hfma2(l1[0], wl1h, __hmul2(h1[0], wh1h))));
            __half2 bp1 = __hfma2(l0[1], wl0h, __hfma2(h0[1], wh0h,
                          __hfma2(l1[1], wl1h, __hmul2(h1[1], wh1h))));
            __half2 bp2 = __hfma2(l0[2], wl0h, __hfma2(h0[2], wh0h,
                          __hfma2(l1[2], wl1h, __hmul2(h1[2], wh1h))));
            __half2 bp3 = __hfma2(l0[3], wl0h, __hfma2(h0[3], wh0h,
                          __hfma2(l1[3], wl1h, __hmul2(h1[3], wh1h))));
            __half2 bpv[4] = {bp0, bp1, bp2, bp3};
            const f16x8 bfrag = *(const f16x8*)bpv;

            const f16x8* af = (const f16x8*)wdf + ((size_t)s * 4) * 64 + lane;
#pragma unroll
            for (int mt = 0; mt < 4; ++mt)
                acc[mt] = __builtin_amdgcn_mfma_f32_16x16x32_f16(
                    af[(size_t)mt * 64], bfrag, acc[mt], 0, 0, 0);
        }
    }

    // ---------------- Epilogue: direct store -------------------------------
#pragma unroll
    for (int mt = 0; mt < 4; ++mt) {
#pragma unroll
        for (int r = 0; r < 4; ++r) {
            const int cout = mt * 16 + kb * 4 + r;
            float v = acc[mt][r] + bdcn[cout];
            v = (v >= 0.f) ? v : 0.1f * v;
            out[((size_t)(b * NF + cout)) * HWSZ + (size_t)y * WWID + x] = v;
        }
    }
}

// ---------------------------------------------------------------------------
extern "C" void kernel_launch(void* const* d_in, const int* in_sizes, int n_in,
                              void* d_out, int out_size, void* d_ws, size_t ws_size,
                              hipStream_t stream)
{
    const float* nbr  = (const float*)d_in[0];
    const float* ref  = (const float*)d_in[1];
    const float* w1   = (const float*)d_in[2];
    const float* b1   = (const float*)d_in[3];
    const float* wom  = (const float*)d_in[4];
    const float* bom  = (const float*)d_in[5];
    const float* wdcn = (const float*)d_in[6];
    const float* bdcn = (const float*)d_in[7];
    float* out = (float*)d_out;

    const size_t NH_B  = (size_t)BB * HWSZ * 128 * 2;     // 16,777,216
    const size_t OFF_B = (size_t)BB * HWSZ * 64 * 2;      //  8,388,608
    const size_t GM_B  = (size_t)BB * HWSZ * 64 * 2 + 64; // + overread pad
    const size_t WF1_B = 36 * 4 * 512 * 2;                //    147,456
    const size_t WF2_B = 18 * 14 * 512 * 2;               //    258,048

    char* ws = (char*)d_ws;
    unsigned short* nhwcin = (unsigned short*)ws;
    unsigned short* off_f  = (unsigned short*)(ws + NH_B);
    unsigned short* gm     = (unsigned short*)(ws + NH_B + OFF_B);
    unsigned short* wf1    = (unsigned short*)(ws + NH_B + OFF_B + GM_B);
    unsigned short* wf2    = wf1 + WF1_B / 2;
    unsigned short* wdf    = wf2 + WF2_B / 2;

    // 1) prep: transpose (NHWC128 bf16 + fp16 gm) and all weight repacks
    prep_kernel<<<1024 + 936, 256, 0, stream>>>(
        nbr, ref, w1, wom, wdcn, nhwcin, gm, wf1, wf2, wdf);

    // 2) conv1: staged-LDS implicit GEMM, XCD swizzle + async pass-2 stage
    conv1_kernel<<<1024, 256, 0, stream>>>(nhwcin, wf1, b1, off_f);

    // 3) fused conv_om + deformable conv (128-px blocks, 8 waves)
    dcn_fused_kernel<<<512, 512, 0, stream>>>(
        off_f, gm, wf2, bom, wdf, bdcn, out);
}